// Round 5
// baseline (1954.525 us; speedup 1.0000x reference)
//
#include <hip/hip_runtime.h>
#include <hip/hip_bf16.h>
#include <cstdint>
#include <cstddef>

// Problem constants
#define H_    128
#define IN_   86
#define OUT_  66
#define T_    50
#define B_    8192
#define NPOSE 15

// Round-10 design: break the same-address L2-slice lockstep.
//  Post-mortem r0-r4: ~25us/step invariant across 5 structures; duration is
//  clock-invariant (cold dispatch: same dur at 6x lower util counters) and
//  insensitive to per-CU demand, ring staging, VGPRs. All throughput pipes
//  sum to <1/3 of the wall. Remaining invariant: every CU on an XCD sweeps
//  the SAME 480KB weight addresses in the SAME order in barrier-lockstep ->
//  each hot line is owned by one L2 slice -> sequential slice-port service
//  ~= the observed wall.
//  Fix: per-block ROTATED k-tile visiting order, rot = (bid>>3) mod KT
//  (bid>>3 is distinct among the 32 XCD-cohort blocks under round-robin
//  dispatch; bid%8 is constant per XCD). Blocks now read different frags at
//  any instant -> parallel slice service. Accumulation order within a gate
//  is fp32-reassociated only (same product set; ~1e-6 deltas, margin 4x).
//  g-order NOT rotated (runtime acc index -> scratch, rule #20).
//  Host: r2 structure (BR=32, 1024thr, fused 2-barrier loop, flat loads) —
//  demand-halving needed once serialization is gone (983KB/CU/step would
//  exceed aggregate L2 BW at the target step time).
// K0 = 224: [u(86)|pad(10)|h1(128)] ; K1 = 256: [h1|h2]
#define K0T 7
#define K1T 8
#define KDT 4
#define NT0 32
#define NT1 32
#define NTD 5
#define S0  232   // A0 row stride (ushorts); 116 dwords = 4*odd (2-way, free)
#define S1  264   // A1 row stride; 132 dwords = 4*odd
#define BR  32
#define THR 1024

// ws layout (bytes) — hi-only packed B fragments
#define B0P_OFF 0
#define B0P_SZ  (K0T * NT0 * 1024)       // 229376
#define B1P_OFF (B0P_OFF + B0P_SZ)
#define B1P_SZ  (K1T * NT1 * 1024)       // 262144
#define BDP_OFF (B1P_OFF + B1P_SZ)       // 491520
#define BDP_SZ  (KDT * NTD * 1024)       // 20480
#define B0P_N (B0P_SZ / 2)               // 114688
#define B1P_N (B1P_SZ / 2)               // 131072
#define TOT_N ((B0P_SZ + B1P_SZ + BDP_SZ) / 2)   // 256000

typedef __attribute__((ext_vector_type(8))) short bfrag;
typedef __attribute__((ext_vector_type(4))) float ffrag;

#define MFMA(AC, AA, BB) \
  AC = __builtin_amdgcn_mfma_f32_16x16x32_bf16((AA), (BB), (AC), 0, 0, 0)

__device__ __forceinline__ unsigned short bf16rn(float f) {
  union { float f; unsigned int u; } cv; cv.f = f;
  unsigned int u = cv.u;
  u += 0x7FFFu + ((u >> 16) & 1u);   // round-to-nearest-even
  return (unsigned short)(u >> 16);
}
__device__ __forceinline__ float bf16tof(unsigned short h) {
  union { unsigned int u; float f; } cv; cv.u = ((unsigned int)h) << 16;
  return cv.f;
}
__device__ __forceinline__ float sigmoid_f(float v) {
  return __fdividef(1.f, 1.f + __expf(-v));
}
__device__ __forceinline__ float tanh_f(float v) {
  float av = fabsf(v);
  float e  = __expf(-2.f * av);
  float t  = __fdividef(1.f - e, 1.f + e);
  return copysignf(t, v);
}

// ---------------- prep: pack hi-only weights in MFMA fragment order ---------
__global__ void wm_prep(
    const float* __restrict__ Wih0, const float* __restrict__ Whh0,
    const float* __restrict__ Wih1, const float* __restrict__ Whh1,
    const float* __restrict__ Wd,
    unsigned short* __restrict__ wsu)
{
  const int idx = blockIdx.x * 256 + threadIdx.x;
  if (idx >= TOT_N) return;
  int region, l;
  if (idx < B0P_N)               { region = 0; l = idx; }
  else if (idx < B0P_N + B1P_N)  { region = 1; l = idx - B0P_N; }
  else                           { region = 2; l = idx - (B0P_N + B1P_N); }

  int k, nt, lane, j;
  if (region < 2) {
    k  = l >> 14;            // 32 tiles * 512 ushorts = 16384 per ktile
    int r1 = l & 16383;
    nt = r1 >> 9;
    int li = r1 & 511;
    lane = li >> 3; j = li & 7;
  } else {
    k  = l / 2560;           // 5 * 512 per ktile
    int r1 = l % 2560;
    nt = r1 >> 9;
    int li = r1 & 511;
    lane = li >> 3; j = li & 7;
  }
  const int n  = nt * 16 + (lane & 15);
  const int kk = k * 32 + (lane >> 4) * 8 + j;

  float v = 0.f;
  if (region == 0) {
    if (kk < IN_)                    v = Wih0[n * IN_ + kk];
    else if (kk >= 96 && kk < 224)   v = Whh0[n * H_ + (kk - 96)];
  } else if (region == 1) {
    v = (kk < H_) ? Wih1[n * H_ + kk] : Whh1[n * H_ + (kk - H_)];
  } else {
    if (n < OUT_)                    v = Wd[n * H_ + kk];
  }
  wsu[idx] = bf16rn(v);
}

// ---------------- GEMM helper: rotated K sweep ------------------------------
// Visits k-tiles kbase + ((j + rot) mod KT); rot is wave-uniform (SGPR).
// acc index g stays compile-time (no runtime-indexed register arrays).
template<int KT>
__device__ __forceinline__ void gemm_rot(const unsigned short* Ah, const unsigned short* Al,
                                         int ab, const char* __restrict__ Bb, int NT,
                                         int kbase, int rot, int uw, int lane16,
                                         ffrag acc[4]) {
  #pragma unroll 2
  for (int j = 0; j < KT; ++j) {
    int k = j + rot; if (k >= KT) k -= KT;
    k += kbase;
    const bfrag ah = *(const bfrag*)(Ah + ab + k * 32);
    const bfrag al = *(const bfrag*)(Al + ab + k * 32);
    #pragma unroll
    for (int g = 0; g < 4; ++g) {
      const bfrag bh =
          *(const bfrag*)(Bb + (size_t)((k * NT + g * 8 + uw) * 1024) + lane16);
      MFMA(acc[g], ah, bh);
      MFMA(acc[g], al, bh);
    }
  }
}

// ---------------- main persistent-recurrence kernel --------------------------
__global__ __launch_bounds__(THR, 4) void wm_main(
    const float* __restrict__ x,
    const char*  __restrict__ wsb,
    const float* __restrict__ bih0, const float* __restrict__ bhh0,
    const float* __restrict__ bih1, const float* __restrict__ bhh1,
    const float* __restrict__ bd,
    float* __restrict__ out)
{
  __shared__ __align__(16) unsigned short A0h[BR * S0];
  __shared__ __align__(16) unsigned short A0l[BR * S0];
  __shared__ __align__(16) unsigned short A1h[BR * S1];
  __shared__ __align__(16) unsigned short A1l[BR * S1];

  const int tid  = threadIdx.x;
  const int lane = tid & 63;
  const int wv   = tid >> 6;      // wave id 0..15
  const int uw   = wv & 7;        // unit-slice id (0..7)
  const int mt   = wv >> 3;       // M-tile (0: rows 0..15, 1: rows 16..31)
  const int ln15 = lane & 15;
  const int quad = lane >> 4;
  const int lane16 = lane * 16;

  // Per-block sweep rotations. bid>>3 is distinct among the 32 blocks that
  // share an XCD under round-robin dispatch (bid%8 would be XCD-constant).
  const int rotu = (int)(blockIdx.x >> 3);
  const int rot1 = rotu & 7;        // B1 full (8 tiles)
  const int rot0 = rotu % 7;        // B0 full (7 tiles)
  const int rotS = rotu & 3;        // tail B0 tiles 3..6 (4 tiles)
  const int rotC = rotu % 3;        // pose B0 tiles 0..2 (3 tiles)
  const int rotD = rotu & 3;        // dense head (4 tiles)

  const char* B0 = wsb + B0P_OFF;
  const char* B1 = wsb + B1P_OFF;
  const char* BD = wsb + BDP_OFF;

  // zero LDS (h/c zero-init; A0 pads [86,96) and [224,232) stay zero)
  for (int i = tid; i < BR * S0; i += THR) { A0h[i] = 0; A0l[i] = 0; }
  for (int i = tid; i < BR * S1; i += THR) { A1h[i] = 0; A1l[i] = 0; }

  // bias preload — this wave's unit col = uw*16 + ln15, per gate g
  float b0r[4], b1r[4];
  #pragma unroll
  for (int g = 0; g < 4; ++g) {
    const int n = g * 128 + uw * 16 + ln15;
    b0r[g] = bih0[n] + bhh0[n];
    b1r[g] = bih1[n] + bhh1[n];
  }
  // dense head: waves with uw<5 own o-tile uw (o = uw*16 + ln15), M-tile mt
  const int od = uw * 16 + ln15;
  const float bdr = (uw < NTD && od < OUT_) ? bd[od] : 0.f;

  float c1[4], c2[4];
  #pragma unroll
  for (int r = 0; r < 4; ++r) { c1[r] = 0.f; c2[r] = 0.f; }

  const int arow = mt * 16 + ln15;         // A-frag source row
  const int a0b  = arow * S0 + quad * 8;
  const int a1b  = arow * S1 + quad * 8;
  const int prow = mt * 16 + quad * 4;     // C/D rows = prow + r
  const int unit = uw * 16 + ln15;         // this lane's unit column
  const int xr_row = tid >> 5;             // staging: 32 rows x 32 lanes
  const int xr_col = tid & 31;

  // pointwise lambdas ---------------------------------------------------------
  auto pw_l1 = [&](const ffrag a4[4]) {    // h1 from acc0; writes A0[96+], A1[0+]
    #pragma unroll
    for (int rr = 0; rr < 4; ++rr) {
      const float ig = sigmoid_f(a4[0][rr]);
      const float fg = sigmoid_f(a4[1][rr]);
      const float gg = tanh_f(a4[2][rr]);
      const float og = sigmoid_f(a4[3][rr]);
      const float c  = fmaf(fg, c1[rr], ig * gg);
      c1[rr] = c;
      const float h  = og * tanh_f(c);
      const unsigned short hi = bf16rn(h);
      const unsigned short lo = bf16rn(h - bf16tof(hi));
      const int row = prow + rr;
      A0h[row * S0 + 96 + unit] = hi;  A0l[row * S0 + 96 + unit] = lo;
      A1h[row * S1 + unit]      = hi;  A1l[row * S1 + unit]      = lo;
    }
  };
  auto pw_l2 = [&](const ffrag a4[4]) {    // h2 from acc1; writes A1[128+]
    #pragma unroll
    for (int rr = 0; rr < 4; ++rr) {
      const float ig = sigmoid_f(a4[0][rr]);
      const float fg = sigmoid_f(a4[1][rr]);
      const float gg = tanh_f(a4[2][rr]);
      const float og = sigmoid_f(a4[3][rr]);
      const float c  = fmaf(fg, c2[rr], ig * gg);
      c2[rr] = c;
      const float h  = og * tanh_f(c);
      const unsigned short hi = bf16rn(h);
      const unsigned short lo = bf16rn(h - bf16tof(hi));
      const int row = prow + rr;
      A1h[row * S1 + 128 + unit] = hi;  A1l[row * S1 + 128 + unit] = lo;
    }
  };
  auto binit = [&](ffrag a4[4], const float bv[4]) {
    #pragma unroll
    for (int g = 0; g < 4; ++g) a4[g] = (ffrag){bv[g], bv[g], bv[g], bv[g]};
  };
  auto stage_write = [&](float v, int idx) {
    const unsigned short hi = bf16rn(v);
    A0h[idx] = hi;
    A0l[idx] = bf16rn(v - bf16tof(hi));
  };

  __syncthreads();   // zero-fill visible before staging overwrites

  // ---- prologue: stage x(0), compute acc0(0) --------------------------------
  {
    const float* xr = x + ((size_t)(blockIdx.x * BR + xr_row) * T_ + 0) * IN_;
    const float v0 = xr[xr_col];
    const float v1 = xr[xr_col + 32];
    float v2 = 0.f;
    if (xr_col < IN_ - 64) v2 = xr[xr_col + 64];
    stage_write(v0, xr_row * S0 + xr_col);
    stage_write(v1, xr_row * S0 + xr_col + 32);
    if (xr_col < IN_ - 64) stage_write(v2, xr_row * S0 + xr_col + 64);
  }
  __syncthreads();

  ffrag acc0[4], acc1[4];
  binit(acc0, b0r);
  gemm_rot<K0T>(A0h, A0l, a0b, B0, NT0, 0, rot0, uw, lane16, acc0);
  __syncthreads();

  // ---- fused main loop: t = 0..49 (2 barriers per timestep) -----------------
  for (int t = 0; t < T_; ++t) {
    // W phase: x loads issued early, pointwise, LDS writes.
    float v0 = 0.f, v1 = 0.f, v2 = 0.f;
    const bool stg = (t < T_ - 1);         // t=49: u(50)=x(49), already staged
    if (stg) {
      const float* xr = x + ((size_t)(blockIdx.x * BR + xr_row) * T_ + (t + 1)) * IN_;
      v0 = xr[xr_col];
      v1 = xr[xr_col + 32];
      if (xr_col < IN_ - 64) v2 = xr[xr_col + 64];
    }
    if (t > 0) pw_l2(acc1);                // h2(t-1)
    pw_l1(acc0);                           // h1(t)
    if (stg) {
      stage_write(v0, xr_row * S0 + xr_col);
      stage_write(v1, xr_row * S0 + xr_col + 32);
      if (xr_col < IN_ - 64) stage_write(v2, xr_row * S0 + xr_col + 64);
    }
    __syncthreads();   // h1(t), h2(t-1), x(t+1) visible

    // G phase: gates1(t) + gates0(t+1) — independent, one fat phase.
    binit(acc1, b1r);
    gemm_rot<K1T>(A1h, A1l, a1b, B1, NT1, 0, rot1, uw, lane16, acc1);
    binit(acc0, b0r);
    gemm_rot<K0T>(A0h, A0l, a0b, B0, NT0, 0, rot0, uw, lane16, acc0);
    __syncthreads();   // all reads done before next W overwrites
  }

  // ---- tail: t = 50..64 (pose feedback breaks full fusion) ------------------
  for (int t = T_; t < T_ + NPOSE; ++t) {
    const bool more = (t < T_ + NPOSE - 1);
    // Wa: h1(t) (+ h2(49) once)
    if (t == T_) pw_l2(acc1);              // h2(49)
    pw_l1(acc0);                           // h1(t)
    __syncthreads();

    // Ga: gates1(t) full + gates0(t+1) k-tiles 3..6 (h1-dependent part)
    binit(acc1, b1r);
    gemm_rot<K1T>(A1h, A1l, a1b, B1, NT1, 0, rot1, uw, lane16, acc1);
    if (more) {
      binit(acc0, b0r);
      gemm_rot<4>(A0h, A0l, a0b, B0, NT0, 3, rotS, uw, lane16, acc0);
    }
    __syncthreads();

    // Wb: h2(t)
    pw_l2(acc1);
    __syncthreads();

    // Gb: dense head (waves with uw<5, both M-tiles), rotated k-sweep
    const int s = t - T_;
    if (uw < NTD) {
      ffrag dacc = (ffrag){bdr, bdr, bdr, bdr};
      #pragma unroll
      for (int j = 0; j < KDT; ++j) {
        const int k = (j + rotD) & 3;
        const bfrag ah = *(const bfrag*)(A1h + a1b + 128 + k * 32);
        const bfrag al = *(const bfrag*)(A1l + a1b + 128 + k * 32);
        const bfrag bh = *(const bfrag*)(BD + (size_t)((k * NTD + uw) * 1024) + lane16);
        MFMA(dacc, ah, bh);
        MFMA(dacc, al, bh);
      }
      if (od < OUT_) {
        #pragma unroll
        for (int rr = 0; rr < 4; ++rr) {
          const int row = prow + rr;
          const float v = dacc[rr];
          out[((size_t)(blockIdx.x * BR + row) * NPOSE + s) * OUT_ + od] = v;
          if (s < NPOSE - 1) {
            const unsigned short hi = bf16rn(v);
            A0h[row * S0 + od] = hi;
            A0l[row * S0 + od] = bf16rn(v - bf16tof(hi));
          }
        }
      }
    }
    __syncthreads();   // pose visible

    // Gc: gates0(t+1) k-tiles 0..2 (pose|cond region). Reads A0[0..96) only;
    // next Wa writes A0[96+]/A1 — disjoint, no barrier needed here.
    if (more) {
      gemm_rot<3>(A0h, A0l, a0b, B0, NT0, 0, rotC, uw, lane16, acc0);
    }
  }
}

extern "C" void kernel_launch(void* const* d_in, const int* in_sizes, int n_in,
                              void* d_out, int out_size, void* d_ws, size_t ws_size,
                              hipStream_t stream)
{
  const float* x    = (const float*)d_in[0];
  const float* Wih0 = (const float*)d_in[1];
  const float* Whh0 = (const float*)d_in[2];
  const float* bih0 = (const float*)d_in[3];
  const float* bhh0 = (const float*)d_in[4];
  const float* Wih1 = (const float*)d_in[5];
  const float* Whh1 = (const float*)d_in[6];
  const float* bih1 = (const float*)d_in[7];
  const float* bhh1 = (const float*)d_in[8];
  const float* Wd   = (const float*)d_in[9];
  const float* bd   = (const float*)d_in[10];

  wm_prep<<<(TOT_N + 255) / 256, 256, 0, stream>>>(Wih0, Whh0, Wih1, Whh1, Wd,
                                                   (unsigned short*)d_ws);
  wm_main<<<B_ / BR, THR, 0, stream>>>(x, (const char*)d_ws,
                                       bih0, bhh0, bih1, bhh1, bd,
                                       (float*)d_out);
}

// Round 6
// 1339.873 us; speedup vs baseline: 1.4587x; 1.4587x over previous
//
#include <hip/hip_runtime.h>
#include <cstdint>
#include <cstddef>

// Problem constants
#define H_    128
#define IN_   86
#define OUT_  66
#define T_    50
#define B_    8192
#define NPOSE 15

// Round-11 design: true counted-vmcnt pipeline + f16 single precision.
//  Post-mortem r0-r5: duration is CLOCK-INVARIANT (~25us/step at both 2.4GHz
//  cold and ~700MHz steady, proven by VALUBusy/VALU-work reconciliation) ->
//  memory-latency wall, not any pipe. r4's ring failed for two reasons:
//  (a) sched_barrier(0) after EVERY frag wait -> 60 scheduling fences/phase;
//  (b) __syncthreads drains vmcnt(0) -> cross-barrier prefetch died at every
//  barrier. Fixes here:
//   - raw barrier = s_waitcnt lgkmcnt(0) + s_barrier (NO vmcnt drain); ring
//     is wave-private so no cross-wave vm visibility needed.
//   - one counted waitvm per KTILE (4 frags), no sched fences; RING=12 slots
//     = 3-ktile lookahead always in flight.
//   - f16 single precision replaces bf16 + hi/lo split: halves MFMA count,
//     A-LDS traffic, pointwise VALU. f16 weights (2^-11 rel) are MORE
//     accurate than bf16-hi (2^-9): predicted absmax ~1.5e-4 (was 9.8e-4).
//   - s_setprio(1) around MFMA clusters (waves phase-diverse via rings).
// K0 = 224: [u(86)|pad(10)|h1(128)] ; K1 = 256: [h1|h2]
#define K0T 7
#define K1T 8
#define KDT 4
#define NTD 5
#define S0  232   // A0 row stride (f16 elems)
#define S1  264   // A1 row stride
#define BR  32
#define THR 512
#define RING 12   // per-wave B-frag ring slots (1KB each) = 3 ktiles lookahead

// ws layout (bytes) — f16 packed B fragments
#define B0P_OFF 0
#define B0P_SZ  (K0T * 32 * 1024)        // 229376
#define B1P_OFF (B0P_OFF + B0P_SZ)
#define B1P_SZ  (K1T * 32 * 1024)        // 262144
#define BDP_OFF (B1P_OFF + B1P_SZ)       // 491520
#define BDP_SZ  (KDT * NTD * 1024)       // 20480
#define B0P_N (B0P_SZ / 2)               // 114688
#define B1P_N (B1P_SZ / 2)               // 131072
#define TOT_N ((B0P_SZ + B1P_SZ + BDP_SZ) / 2)   // 256000

typedef __attribute__((ext_vector_type(8))) _Float16 hfrag;
typedef __attribute__((ext_vector_type(4))) float   ffrag;

#define MFMA16(AC, AA, BB) \
  AC = __builtin_amdgcn_mfma_f32_16x16x32_f16((AA), (BB), (AC), 0, 0, 0)

template <int N> struct IC { static constexpr int value = N; };
template <int N, class F>
__device__ __forceinline__ void cfor(F&& f) {
  if constexpr (N > 0) {
    cfor<N - 1>(static_cast<F&&>(f));
    f(IC<N - 1>{});
  }
}

template<int MODE>
constexpr int kt_of() { return MODE==0?15: MODE==1?12: MODE==2?8: MODE==3?3: 7; }

template <int N>
__device__ __forceinline__ void waitvm() {
  asm volatile("s_waitcnt vmcnt(%0)" :: "i"(N) : "memory");
}

__device__ __forceinline__ void gload_lds16(const void* g, void* l) {
  __builtin_amdgcn_global_load_lds(
      (const __attribute__((address_space(1))) unsigned int*)g,
      (__attribute__((address_space(3))) unsigned int*)l,
      16, 0, 0);
}

__device__ __forceinline__ unsigned short f16rn(float f) {
  union { _Float16 h; unsigned short u; } cv;
  cv.h = (_Float16)f;               // v_cvt_f16_f32, RTE
  return cv.u;
}
__device__ __forceinline__ float sigmoid_f(float v) {
  return __fdividef(1.f, 1.f + __expf(-v));
}
__device__ __forceinline__ float tanh_f(float v) {
  float av = fabsf(v);
  float e  = __expf(-2.f * av);
  float t  = __fdividef(1.f - e, 1.f + e);
  return copysignf(t, v);
}

// ---------------- prep: pack f16 weights in MFMA fragment order -------------
__global__ void wm_prep(
    const float* __restrict__ Wih0, const float* __restrict__ Whh0,
    const float* __restrict__ Wih1, const float* __restrict__ Whh1,
    const float* __restrict__ Wd,
    unsigned short* __restrict__ wsu)
{
  const int idx = blockIdx.x * 256 + threadIdx.x;
  if (idx >= TOT_N) return;
  int region, l;
  if (idx < B0P_N)               { region = 0; l = idx; }
  else if (idx < B0P_N + B1P_N)  { region = 1; l = idx - B0P_N; }
  else                           { region = 2; l = idx - (B0P_N + B1P_N); }

  int k, nt, lane, j;
  if (region < 2) {
    k  = l >> 14;            // 32 tiles * 512 f16 = 16384 per ktile
    int r1 = l & 16383;
    nt = r1 >> 9;
    int li = r1 & 511;
    lane = li >> 3; j = li & 7;
  } else {
    k  = l / 2560;           // 5 * 512 per ktile
    int r1 = l % 2560;
    nt = r1 >> 9;
    int li = r1 & 511;
    lane = li >> 3; j = li & 7;
  }
  const int n  = nt * 16 + (lane & 15);
  const int kk = k * 32 + (lane >> 4) * 8 + j;

  float v = 0.f;
  if (region == 0) {
    if (kk < IN_)                    v = Wih0[n * IN_ + kk];
    else if (kk >= 96 && kk < 224)   v = Whh0[n * H_ + (kk - 96)];
  } else if (region == 1) {
    v = (kk < H_) ? Wih1[n * H_ + kk] : Whh1[n * H_ + (kk - H_)];
  } else {
    if (n < OUT_)                    v = Wd[n * H_ + kk];
  }
  wsu[idx] = f16rn(v);
}

// ---------------- main persistent-recurrence kernel --------------------------
// GEMM modes (ktile j -> source):
//  0: fused main (KT=15): j<8 -> B1 k=j ; else B0 k=j-8
//  1: tail Ga full (KT=12): j<8 -> B1 k=j ; else B0 k=3+(j-8)
//  2: tail Ga last (KT=8): B1 k=j
//  3: pose Gc (KT=3): B0 k=j
//  4: init gemm0 (KT=7): B0 k=j
__global__ __launch_bounds__(THR, 2) void wm_main(
    const float* __restrict__ x,
    const char*  __restrict__ wsb,
    const float* __restrict__ bih0, const float* __restrict__ bhh0,
    const float* __restrict__ bih1, const float* __restrict__ bhh1,
    const float* __restrict__ bd,
    float* __restrict__ out)
{
  __shared__ __align__(16) unsigned short A0h[BR * S0];   // 14848 B
  __shared__ __align__(16) unsigned short A1h[BR * S1];   // 16896 B
  __shared__ __align__(16) char RG[8][RING * 1024];       // 98304 B

  const int tid  = threadIdx.x;
  const int lane = tid & 63;
  const int uw   = tid >> 6;      // wave id = unit-slice id (0..7)
  const int ln15 = lane & 15;
  const int quad = lane >> 4;
  const int quad4 = quad * 4;
  const int lane16 = lane * 16;

  const char* B0 = wsb + B0P_OFF;
  const char* B1 = wsb + B1P_OFF;
  const char* BD = wsb + BDP_OFF;
  char* myring = &RG[uw][0];
  const _Float16* A0f = (const _Float16*)A0h;
  const _Float16* A1f = (const _Float16*)A1h;

  // zero LDS (h/c zero-init; A0 pads [86,96) and [224,232) stay zero)
  for (int i = tid; i < BR * S0; i += THR) A0h[i] = 0;
  for (int i = tid; i < BR * S1; i += THR) A1h[i] = 0;

  // bias preload — this wave's unit col = uw*16 + ln15, per gate g
  float b0r[4], b1r[4];
  #pragma unroll
  for (int g = 0; g < 4; ++g) {
    const int n = g * 128 + uw * 16 + ln15;
    b0r[g] = bih0[n] + bhh0[n];
    b1r[g] = bih1[n] + bhh1[n];
  }
  const int od = uw * 16 + ln15;
  const float bdr = (uw < NTD && od < OUT_) ? bd[od] : 0.f;

  float c1[2][4], c2[2][4];
  #pragma unroll
  for (int m = 0; m < 2; ++m)
    #pragma unroll
    for (int r = 0; r < 4; ++r) { c1[m][r] = 0.f; c2[m][r] = 0.f; }

  // A-frag offsets (element units) for the two M-tiles this wave covers
  const int a0b0 = ln15 * S0 + quad * 8;
  const int a0b1 = (16 + ln15) * S0 + quad * 8;
  const int a1b0 = ln15 * S1 + quad * 8;
  const int a1b1 = (16 + ln15) * S1 + quad * 8;
  const int unit = uw * 16 + ln15;
  const int xr_row = tid >> 4;             // staging: 32 rows x 16 lanes
  const int xr_col = tid & 15;

  ffrag acc0[2][4], acc1[2][4];

  // ------ lambdas ------------------------------------------------------------
  auto binit0 = [&]() {
    #pragma unroll
    for (int m = 0; m < 2; ++m)
      #pragma unroll
      for (int g = 0; g < 4; ++g) acc0[m][g] = (ffrag){b0r[g], b0r[g], b0r[g], b0r[g]};
  };
  auto binit1 = [&]() {
    #pragma unroll
    for (int m = 0; m < 2; ++m)
      #pragma unroll
      for (int g = 0; g < 4; ++g) acc1[m][g] = (ffrag){b1r[g], b1r[g], b1r[g], b1r[g]};
  };
  auto pw_l1 = [&]() {    // h1 from acc0; writes A0[96+], A1[0+]
    #pragma unroll
    for (int m = 0; m < 2; ++m)
      #pragma unroll
      for (int rr = 0; rr < 4; ++rr) {
        const float ig = sigmoid_f(acc0[m][0][rr]);
        const float fg = sigmoid_f(acc0[m][1][rr]);
        const float gg = tanh_f(acc0[m][2][rr]);
        const float og = sigmoid_f(acc0[m][3][rr]);
        const float c  = fmaf(fg, c1[m][rr], ig * gg);
        c1[m][rr] = c;
        const float h  = og * tanh_f(c);
        const unsigned short hv = f16rn(h);
        const int row = m * 16 + quad4 + rr;
        A0h[row * S0 + 96 + unit] = hv;
        A1h[row * S1 + unit]      = hv;
      }
  };
  auto pw_l2 = [&]() {    // h2 from acc1; writes A1[128+]
    #pragma unroll
    for (int m = 0; m < 2; ++m)
      #pragma unroll
      for (int rr = 0; rr < 4; ++rr) {
        const float ig = sigmoid_f(acc1[m][0][rr]);
        const float fg = sigmoid_f(acc1[m][1][rr]);
        const float gg = tanh_f(acc1[m][2][rr]);
        const float og = sigmoid_f(acc1[m][3][rr]);
        const float c  = fmaf(fg, c2[m][rr], ig * gg);
        c2[m][rr] = c;
        const float h  = og * tanh_f(c);
        const int row = m * 16 + quad4 + rr;
        A1h[row * S1 + 128 + unit] = f16rn(h);
      }
  };

  // issue the 4 B-frags of ktile i for MODE into the ring
  auto issue_jt = [&](auto mc2, auto jc2) {
    constexpr int MODE = decltype(mc2)::value;
    constexpr int i = decltype(jc2)::value;
    constexpr bool i1 = (MODE <= 2) && (i < K1T);
    constexpr int ik = MODE==0 ? (i1 ? i : i - 8)
                     : MODE==1 ? (i1 ? i : 3 + (i - 8))
                     : i;
    constexpr int ISB = (4 * i) % RING;
    const char* src = (i1 ? B1 : B0) + (size_t)ik * 32 * 1024;
    #pragma unroll
    for (int g = 0; g < 4; ++g)
      gload_lds16(src + (size_t)(g * 8 + uw) * 1024 + lane16,
                  myring + (ISB + g) * 1024);
  };
  auto prefetch_g = [&](auto mc2) {
    constexpr int MODE = decltype(mc2)::value;
    constexpr int NP = kt_of<MODE>() < 3 ? kt_of<MODE>() : 3;
    cfor<NP>([&](auto jc) { issue_jt(mc2, jc); });
  };

  // staged GEMM: one counted vmcnt per ktile; issues ktile j+3 after consume.
  auto run_gemm = [&](auto mc, auto pfc) {
    constexpr int MODE = decltype(mc)::value;
    constexpr bool PF = decltype(pfc)::value != 0;
    constexpr int KT = kt_of<MODE>();
    if constexpr (!PF) prefetch_g(mc);
    cfor<KT>([&](auto jc) {
      constexpr int j = decltype(jc)::value;
      constexpr bool is1 = (MODE <= 2) && (j < K1T);
      constexpr int k = MODE==0 ? (is1 ? j : j - 8)
                      : MODE==1 ? (is1 ? j : 3 + (j - 8))
                      : j;
      constexpr int REM = KT - 1 - j;
      constexpr int W = 4 * (REM < 2 ? REM : 2);
      waitvm<W>();                       // ktile j's 4 frags have landed
      hfrag a0, a1;
      if constexpr (is1) {
        a0 = *(const hfrag*)(A1f + a1b0 + k * 32);
        a1 = *(const hfrag*)(A1f + a1b1 + k * 32);
      } else {
        a0 = *(const hfrag*)(A0f + a0b0 + k * 32);
        a1 = *(const hfrag*)(A0f + a0b1 + k * 32);
      }
      constexpr int SB = (4 * j) % RING;
      __builtin_amdgcn_s_setprio(1);
      #pragma unroll
      for (int g = 0; g < 4; ++g) {
        const hfrag bh = *(const hfrag*)(myring + (SB + g) * 1024 + lane16);
        if constexpr (is1) { MFMA16(acc1[0][g], a0, bh); MFMA16(acc1[1][g], a1, bh); }
        else               { MFMA16(acc0[0][g], a0, bh); MFMA16(acc0[1][g], a1, bh); }
      }
      __builtin_amdgcn_s_setprio(0);
      if constexpr (j + 3 < KT) issue_jt(mc, IC<j + 3>{});
    });
  };

  // raw barrier: drain LDS ops for cross-wave visibility, do NOT drain vmcnt
  // (ring gloads are wave-private) — keeps the prefetch pipeline alive.
  auto barrier2 = [&]() {
    asm volatile("s_waitcnt lgkmcnt(0)" ::: "memory");
    __builtin_amdgcn_s_barrier();
    asm volatile("" ::: "memory");
  };

  auto stage_x = [&](int t) {
    const float* xr = x + ((size_t)(blockIdx.x * BR + xr_row) * T_ + t) * IN_;
    float xv[6];
    #pragma unroll
    for (int m = 0; m < 6; ++m) {
      const int k = xr_col + m * 16;
      xv[m] = (k < IN_) ? xr[k] : 0.f;
    }
    #pragma unroll
    for (int m = 0; m < 6; ++m) {
      const int k = xr_col + m * 16;
      if (k < IN_) A0h[xr_row * S0 + k] = f16rn(xv[m]);
    }
  };

  barrier2();   // zero-fill visible

  // ---- prologue: stage x(0), prefetch, compute acc0(0) ----------------------
  stage_x(0);
  prefetch_g(IC<4>{});
  barrier2();
  binit0();
  run_gemm(IC<4>{}, IC<1>{});
  barrier2();

  // ---- fused main loop: t = 0..49 (2 raw barriers per timestep) -------------
  for (int t = 0; t < T_; ++t) {
    // W phase: x loads + ring prefetch issued first (latency hides under
    // pointwise), then pointwise, then LDS writes.
    prefetch_g(IC<0>{});
    if (t < T_ - 1) {                  // t=49: u(50)=x(49), already staged
      stage_x(t + 1);
      if (t > 0) pw_l2();
      pw_l1();
    } else {
      if (t > 0) pw_l2();
      pw_l1();
    }
    barrier2();   // h1(t), h2(t-1), x(t+1) visible; prefetch still in flight

    // G phase: gates1(t) + gates0(t+1) — one fat staged phase.
    binit1();
    binit0();
    run_gemm(IC<0>{}, IC<1>{});
    barrier2();   // all reads done before next W overwrites
  }

  // ---- tail: t = 50..64 (pose feedback breaks full fusion) ------------------
  for (int t = T_; t < T_ + NPOSE; ++t) {
    const bool more = (t < T_ + NPOSE - 1);
    // Wa: prefetch Ga (first 3 ktiles identical for modes 1/2), h1(t)
    prefetch_g(IC<2>{});
    if (t == T_) pw_l2();              // h2(49)
    pw_l1();                           // h1(t)
    barrier2();

    // Ga: gates1(t) full + (if more) gates0(t+1) k-tiles 3..6
    binit1();
    if (more) { binit0(); run_gemm(IC<1>{}, IC<1>{}); }
    else      { run_gemm(IC<2>{}, IC<1>{}); }
    barrier2();

    // Wb: h2(t)
    pw_l2();
    barrier2();

    // Gb: dense head (waves with uw<5, both M-tiles)
    const int s = t - T_;
    if (uw < NTD) {
      ffrag d0 = (ffrag){bdr, bdr, bdr, bdr};
      ffrag d1 = (ffrag){bdr, bdr, bdr, bdr};
      #pragma unroll
      for (int k = 0; k < KDT; ++k) {
        const hfrag ah0 = *(const hfrag*)(A1f + a1b0 + 128 + k * 32);
        const hfrag ah1 = *(const hfrag*)(A1f + a1b1 + 128 + k * 32);
        const hfrag bh  = *(const hfrag*)(BD + (size_t)(k * NTD + uw) * 1024 + lane16);
        MFMA16(d0, ah0, bh);
        MFMA16(d1, ah1, bh);
      }
      if (od < OUT_) {
        #pragma unroll
        for (int m = 0; m < 2; ++m)
          #pragma unroll
          for (int rr = 0; rr < 4; ++rr) {
            const int row = m * 16 + quad4 + rr;
            const float v = m ? d1[rr] : d0[rr];
            out[((size_t)(blockIdx.x * BR + row) * NPOSE + s) * OUT_ + od] = v;
            if (s < NPOSE - 1) A0h[row * S0 + od] = f16rn(v);
          }
      }
    }
    barrier2();   // pose visible

    // Gc: gates0(t+1) k-tiles 0..2 (pose|cond region), self-prefetching.
    // Reads A0[0..96) only; next Wa writes A0[96+]/A1 — disjoint.
    if (more) run_gemm(IC<3>{}, IC<0>{});
  }
}

extern "C" void kernel_launch(void* const* d_in, const int* in_sizes, int n_in,
                              void* d_out, int out_size, void* d_ws, size_t ws_size,
                              hipStream_t stream)
{
  const float* x    = (const float*)d_in[0];
  const float* Wih0 = (const float*)d_in[1];
  const float* Whh0 = (const float*)d_in[2];
  const float* bih0 = (const float*)d_in[3];
  const float* bhh0 = (const float*)d_in[4];
  const float* Wih1 = (const float*)d_in[5];
  const float* Whh1 = (const float*)d_in[6];
  const float* bih1 = (const float*)d_in[7];
  const float* bhh1 = (const float*)d_in[8];
  const float* Wd   = (const float*)d_in[9];
  const float* bd   = (const float*)d_in[10];

  wm_prep<<<(TOT_N + 255) / 256, 256, 0, stream>>>(Wih0, Whh0, Wih1, Whh1, Wd,
                                                   (unsigned short*)d_ws);
  wm_main<<<B_ / BR, THR, 0, stream>>>(x, (const char*)d_ws,
                                       bih0, bhh0, bih1, bhh1, bd,
                                       (float*)d_out);
}